// Round 8
// baseline (287.225 us; speedup 1.0000x reference)
//
#include <hip/hip_runtime.h>
#include <cmath>

// Problem constants (B=4, S=4096, D=4096, E=64, K=8)
#define NTOK 16384
#define DDIM 4096
#define NEXP 64
#define TOPK 8
#define TPB    32               // tokens per block
#define KSPLIT 4                // K-split ways (waves: 4 expgrp x 4 ksplit)
#define KSL    (DDIM / KSPLIT)  // 1024 K per wave
#define KSTEPS (KSL / 32)       // 32 steps of 32 k
#define EPS_GAP 2.5e-4f         // ambiguity margin; trunc-split GEMM err sigma ~2e-5

typedef __attribute__((ext_vector_type(8))) short short8;   // 8 bf16
typedef __attribute__((ext_vector_type(4))) float f32x4;

// trunc split: hi = top 16 bits (residual exact), lo = trunc16(f - hi).
#define CVT1(f, hOut, lOut, j) do {                                          \
    unsigned _u = __builtin_bit_cast(unsigned, (float)(f));                  \
    float _hf = __builtin_bit_cast(float, _u & 0xFFFF0000u);                 \
    hOut[j] = (short)(_u >> 16);                                             \
    lOut[j] = (short)(__builtin_bit_cast(unsigned, (float)((f) - _hf)) >> 16);\
} while (0)
#define CONV8(vA, vB, hOut, lOut) do {                       \
    CVT1(vA.x, hOut, lOut, 0); CVT1(vA.y, hOut, lOut, 1);    \
    CVT1(vA.z, hOut, lOut, 2); CVT1(vA.w, hOut, lOut, 3);    \
    CVT1(vB.x, hOut, lOut, 4); CVT1(vB.y, hOut, lOut, 5);    \
    CVT1(vB.z, hOut, lOut, 6); CVT1(vB.w, hOut, lOut, 7);    \
} while (0)

// ---------------------------------------------------------------------------
// Kernel 0: pack W[4096][64] fp32 into fragment-lane order bf16 hi/lo blob:
// blob[c][eg][h][lane*16B], lane = kgrp*16 + e_local, c = 32-k window.
// A wave's B-read per step is then two contiguous 1KB segments (L2-hit).
// 128 c x 8 KB = 1 MB. Also zeroes the flag counter.
// ---------------------------------------------------------------------------
__global__ __launch_bounds__(256) void prep_w(const float* __restrict__ W,
                                              unsigned char* __restrict__ blob,
                                              int* __restrict__ flag_cnt)
{
    __shared__ float tile[32][65];
    const int c = blockIdx.x;                 // k-window [c*32, c*32+32)
    const int t = threadIdx.x;
    if (c == 0 && t == 0) *flag_cnt = 0;
    {
        const int r = t >> 3, q = t & 7;      // row, 8-float slice
        float4 v0 = *reinterpret_cast<const float4*>(
            &W[(size_t)(c * 32 + r) * NEXP + q * 8]);
        float4 v1 = *reinterpret_cast<const float4*>(
            &W[(size_t)(c * 32 + r) * NEXP + q * 8 + 4]);
        tile[r][q * 8 + 0] = v0.x; tile[r][q * 8 + 1] = v0.y;
        tile[r][q * 8 + 2] = v0.z; tile[r][q * 8 + 3] = v0.w;
        tile[r][q * 8 + 4] = v1.x; tile[r][q * 8 + 5] = v1.y;
        tile[r][q * 8 + 6] = v1.z; tile[r][q * 8 + 7] = v1.w;
    }
    __syncthreads();
    {
        const int el   = t & 15;
        const int kgrp = (t >> 4) & 3;
        const int eg   = t >> 6;
        short8 hv, lv;
#pragma unroll
        for (int j = 0; j < 8; ++j) {
            float f = tile[kgrp * 8 + j][eg * 16 + el];
            CVT1(f, hv, lv, j);
        }
        unsigned char* base = blob + (size_t)c * 8192 + eg * 2048 +
                              (kgrp * 16 + el) * 16;
        *reinterpret_cast<short8*>(base)        = hv;   // hi
        *reinterpret_cast<short8*>(base + 1024) = lv;   // lo
    }
}

// ---------------------------------------------------------------------------
// Kernel 1: barrier-free direct-load MFMA GEMM.
// 512 blocks x 1024 thr (16 waves = 4 expgrp x 4 ksplit).
// Wave = 32 tokens x 16 experts over 1024 K (32 steps of 32).
// A: direct global dwordx4 fragment loads (rows consume full 128B lines).
// B: contiguous 1KB wave reads from the pre-packed L2-resident blob.
// No __syncthreads in the K loop; K-split reduced in LDS at the end.
// ---------------------------------------------------------------------------
__global__ __launch_bounds__(1024, 4) void bulk_kernel(
    const float* __restrict__ x, const unsigned char* __restrict__ blob,
    const float* __restrict__ b,
    float* __restrict__ g_out, float* __restrict__ i_out,
    float* __restrict__ s_out,
    int* __restrict__ flag_cnt, int* __restrict__ flag_list, int flag_cap)
{
    __shared__ float red[KSPLIT][TPB][NEXP + 4];   // 34.8 KB
    __shared__ float ls[TPB][NEXP + 1];            // 8.3 KB

    const int tid  = threadIdx.x;
    const int l    = tid & 63;
    const int w    = tid >> 6;
    const int tok0 = blockIdx.x * TPB;

    const int eg   = w & 3;                  // expert group (16 experts)
    const int ks   = w >> 2;                 // K-split slice
    const int mt   = l & 15;                 // token row within frag
    const int kgrp = l >> 4;                 // k-subgroup (8 k elems)

    const float* aptr0 = x + (size_t)(tok0 + mt) * DDIM + ks * KSL + kgrp * 8;
    const float* aptr1 = aptr0 + (size_t)16 * DDIM;
    const unsigned char* bptr = blob + (size_t)(ks * KSTEPS) * 8192 +
                                eg * 2048 + l * 16;

    f32x4 acc0 = (f32x4){0.f, 0.f, 0.f, 0.f};
    f32x4 acc1 = (f32x4){0.f, 0.f, 0.f, 0.f};

#pragma unroll 2
    for (int c = 0; c < KSTEPS; ++c) {
        const float* pa0 = aptr0 + c * 32;
        const float* pa1 = aptr1 + c * 32;
        const unsigned char* pb = bptr + (size_t)c * 8192;
        float4 A00 = *reinterpret_cast<const float4*>(pa0);
        float4 A01 = *reinterpret_cast<const float4*>(pa0 + 4);
        float4 A10 = *reinterpret_cast<const float4*>(pa1);
        float4 A11 = *reinterpret_cast<const float4*>(pa1 + 4);
        short8 bh = *reinterpret_cast<const short8*>(pb);
        short8 bl = *reinterpret_cast<const short8*>(pb + 1024);
        short8 ah0, al0, ah1, al1;
        CONV8(A00, A01, ah0, al0);
        CONV8(A10, A11, ah1, al1);
        acc0 = __builtin_amdgcn_mfma_f32_16x16x32_bf16(ah0, bh, acc0, 0, 0, 0);
        acc0 = __builtin_amdgcn_mfma_f32_16x16x32_bf16(ah0, bl, acc0, 0, 0, 0);
        acc0 = __builtin_amdgcn_mfma_f32_16x16x32_bf16(al0, bh, acc0, 0, 0, 0);
        acc1 = __builtin_amdgcn_mfma_f32_16x16x32_bf16(ah1, bh, acc1, 0, 0, 0);
        acc1 = __builtin_amdgcn_mfma_f32_16x16x32_bf16(ah1, bl, acc1, 0, 0, 0);
        acc1 = __builtin_amdgcn_mfma_f32_16x16x32_bf16(al1, bh, acc1, 0, 0, 0);
    }

    // ---- K-split partials -> LDS (C-frag: col=l&15=expert, row=kgrp*4+r) ----
#pragma unroll
    for (int r = 0; r < 4; ++r) {
        red[ks][kgrp * 4 + r][eg * 16 + mt]      = acc0[r];
        red[ks][16 + kgrp * 4 + r][eg * 16 + mt] = acc1[r];
    }
    __syncthreads();

    // ---- fixed-order reduce + bias + sigmoid + s_out + logits ----
    if (tid < 512) {
        const int t  = tid >> 4;             // token 0..31
        const int e0 = (tid & 15) * 4;       // expert base
        float4 v0 = *reinterpret_cast<const float4*>(&red[0][t][e0]);
        float4 v1 = *reinterpret_cast<const float4*>(&red[1][t][e0]);
        float4 v2 = *reinterpret_cast<const float4*>(&red[2][t][e0]);
        float4 v3 = *reinterpret_cast<const float4*>(&red[3][t][e0]);
        float4 bv = *reinterpret_cast<const float4*>(&b[e0]);
        float s0 = ((v0.x + v1.x) + (v2.x + v3.x)) + bv.x;
        float s1 = ((v0.y + v1.y) + (v2.y + v3.y)) + bv.y;
        float s2 = ((v0.z + v1.z) + (v2.z + v3.z)) + bv.z;
        float s3 = ((v0.w + v1.w) + (v2.w + v3.w)) + bv.w;
        ls[t][e0 + 0] = s0; ls[t][e0 + 1] = s1;
        ls[t][e0 + 2] = s2; ls[t][e0 + 3] = s3;
        float4 sv;
        sv.x = 1.0f / (1.0f + __expf(-s0));
        sv.y = 1.0f / (1.0f + __expf(-s1));
        sv.z = 1.0f / (1.0f + __expf(-s2));
        sv.w = 1.0f / (1.0f + __expf(-s3));
        *reinterpret_cast<float4*>(&s_out[(size_t)(tok0 + t) * NEXP + e0]) = sv;
    }
    __syncthreads();

    // ---- top-10 scan, one lane per token ----
    if (tid < TPB) {
        const int t = tid;
        float val[10];
        int   idx[10];
#pragma unroll
        for (int j = 0; j < 10; ++j) { val[j] = -1e30f; idx[j] = 0; }

        for (int e = 0; e < NEXP; ++e) {
            float v = ls[t][e];
            int  ei = e;
#pragma unroll
            for (int j = 0; j < 10; ++j) {
                if (v > val[j]) {    // strict > keeps lower index first on ties
                    float tv = val[j]; val[j] = v; v = tv;
                    int   ti = idx[j]; idx[j] = ei; ei = ti;
                }
            }
        }

        bool flag = false;
#pragma unroll
        for (int j = 0; j < 9; ++j) flag |= (val[j] - val[j + 1]) < EPS_GAP;

        float g[TOPK], gsum = 0.0f;
#pragma unroll
        for (int j = 0; j < TOPK; ++j) {
            g[j] = 1.0f / (1.0f + __expf(-val[j]));
            gsum += g[j];
        }
        const float inv = 1.0f / gsum;
        const int tg = tok0 + t;
#pragma unroll
        for (int j = 0; j < TOPK; ++j) {
            g_out[(size_t)tg * TOPK + j] = g[j] * inv;
            i_out[(size_t)tg * TOPK + j] = (float)idx[j];
        }
        if (flag) {
            int p = atomicAdd(flag_cnt, 1);
            if (p < flag_cap) flag_list[p] = tg;
        }
    }
}

// ---------------------------------------------------------------------------
// Kernel 2: f64-exact re-rank of ambiguous tokens.
// ---------------------------------------------------------------------------
__global__ __launch_bounds__(256) void refine_kernel(
    const float* __restrict__ x, const float* __restrict__ W,
    const float* __restrict__ b, float* __restrict__ g_out,
    float* __restrict__ i_out, float* __restrict__ s_out,
    const int* __restrict__ flag_cnt, const int* __restrict__ flag_list,
    int flag_cap)
{
    __shared__ float  xs2[DDIM];
    __shared__ double red[4][NEXP];
    __shared__ double sc[NEXP];

    const int tid = threadIdx.x;
    int count = *flag_cnt;
    if (count > flag_cap) count = flag_cap;

    for (int it = blockIdx.x; it < count; it += gridDim.x) {
        const int tok = flag_list[it];
        __syncthreads();
#pragma unroll
        for (int q = 0; q < 4; ++q) {
            int fi = tid + 256 * q;
            *reinterpret_cast<float4*>(&xs2[fi * 4]) =
                *reinterpret_cast<const float4*>(&x[(size_t)tok * DDIM + fi * 4]);
        }
        __syncthreads();

        const int e    = tid & 63;
        const int part = tid >> 6;
        const int dbase = part * (DDIM / 4);
        double a = 0.0;
        for (int d = 0; d < DDIM / 4; ++d) {
            a = fma((double)xs2[dbase + d],
                    (double)W[(size_t)(dbase + d) * NEXP + e], a);
        }
        red[part][e] = a;
        __syncthreads();

        if (tid < NEXP) {
            double z = ((red[0][tid] + red[1][tid]) +
                        (red[2][tid] + red[3][tid])) + (double)b[tid];
            double s = 1.0 / (1.0 + exp(-z));
            sc[tid] = s;
            s_out[(size_t)tok * NEXP + tid] = (float)s;
        }
        __syncthreads();

        if (tid == 0) {
            double val[TOPK];
            int    idx[TOPK];
#pragma unroll
            for (int j = 0; j < TOPK; ++j) { val[j] = -1e30; idx[j] = 0; }
            for (int e2 = 0; e2 < NEXP; ++e2) {
                double v = sc[e2];
                int   ei = e2;
#pragma unroll
                for (int j = 0; j < TOPK; ++j) {
                    if (v > val[j]) {
                        double tv = val[j]; val[j] = v; v = tv;
                        int    ti = idx[j]; idx[j] = ei; ei = ti;
                    }
                }
            }
            double gsum = 0.0;
#pragma unroll
            for (int j = 0; j < TOPK; ++j) gsum += val[j];
            const double inv = 1.0 / gsum;
#pragma unroll
            for (int j = 0; j < TOPK; ++j) {
                g_out[(size_t)tok * TOPK + j] = (float)(val[j] * inv);
                i_out[(size_t)tok * TOPK + j] = (float)idx[j];
            }
        }
        __syncthreads();
    }
}

// ---------------------------------------------------------------------------
extern "C" void kernel_launch(void* const* d_in, const int* in_sizes, int n_in,
                              void* d_out, int out_size, void* d_ws, size_t ws_size,
                              hipStream_t stream)
{
    (void)in_sizes; (void)n_in; (void)out_size;
    const float* x = (const float*)d_in[0];
    const float* W = (const float*)d_in[1];
    const float* b = (const float*)d_in[2];

    float* g_out = (float*)d_out;                       // [NTOK, 8]
    float* i_out = g_out + (size_t)NTOK * TOPK;         // [NTOK, 8] indices as float
    float* s_out = i_out + (size_t)NTOK * TOPK;         // [NTOK, 64]

    const size_t OFF_BLOB = 131072;
    const size_t WS_NEED  = OFF_BLOB + 128u * 8192u;    // +1 MB blob
    if (ws_size < WS_NEED) return;

    char* ws = (char*)d_ws;
    int* cnt  = (int*)ws;
    int* list = (int*)(ws + 16);
    unsigned char* blob = (unsigned char*)(ws + OFF_BLOB);
    int cap = NTOK;

    prep_w<<<DDIM / 32, 256, 0, stream>>>(W, blob, cnt);
    bulk_kernel<<<NTOK / TPB, 1024, 0, stream>>>(x, blob, b,
                                                 g_out, i_out, s_out,
                                                 cnt, list, cap);
    refine_kernel<<<256, 256, 0, stream>>>(x, W, b, g_out, i_out, s_out,
                                           cnt, list, cap);
}

// Round 9
// 212.784 us; speedup vs baseline: 1.3498x; 1.3498x over previous
//
#include <hip/hip_runtime.h>
#include <cmath>

// Problem constants (B=4, S=4096, D=4096, E=64, K=8)
#define NTOK 16384
#define DDIM 4096
#define NEXP 64
#define TOPK 8
#define TPB   32                // tokens per block
#define BK    32                // K per staged step
#define NSTEP (DDIM / BK)       // 128
#define NBUF  6                 // pipeline depth (prefetch distance 5)
#define BUFSZ 12288             // 4 KB A + 8 KB B per step
#define EPS_GAP 2.5e-4f         // ambiguity margin; trunc-split GEMM err ~5e-6 sigma

typedef __attribute__((ext_vector_type(8))) short short8;   // 8 bf16
typedef __attribute__((ext_vector_type(4))) float f32x4;

__device__ __forceinline__ void gload16(const void* g, void* l) {
    __builtin_amdgcn_global_load_lds(
        (const __attribute__((address_space(1))) unsigned int*)g,
        (__attribute__((address_space(3))) unsigned int*)l, 16, 0, 0);
}

// trunc split: hi = top 16 bits (residual exact), lo = trunc16(f - hi).
#define CVT1(f, hOut, lOut, j) do {                                          \
    unsigned _u = __builtin_bit_cast(unsigned, (float)(f));                  \
    float _hf = __builtin_bit_cast(float, _u & 0xFFFF0000u);                 \
    hOut[j] = (short)(_u >> 16);                                             \
    lOut[j] = (short)(__builtin_bit_cast(unsigned, (float)((f) - _hf)) >> 16);\
} while (0)
#define CONV8(vA, vB, hOut, lOut) do {                       \
    CVT1(vA.x, hOut, lOut, 0); CVT1(vA.y, hOut, lOut, 1);    \
    CVT1(vA.z, hOut, lOut, 2); CVT1(vA.w, hOut, lOut, 3);    \
    CVT1(vB.x, hOut, lOut, 4); CVT1(vB.y, hOut, lOut, 5);    \
    CVT1(vB.z, hOut, lOut, 6); CVT1(vB.w, hOut, lOut, 7);    \
} while (0)

// ---------------------------------------------------------------------------
// Kernel 0: pack W into per-step 8KB swizzled B images.
// Image c: expert e row = 128B: [hi 64B | lo 64B], 16B granules, byte offset
// within row XOR ((e&7)<<4). Staging is then linear; ds_reads 2-way max.
// ---------------------------------------------------------------------------
__global__ __launch_bounds__(256) void prep_w(const float* __restrict__ W,
                                              unsigned char* __restrict__ blob,
                                              int* __restrict__ flag_cnt)
{
    __shared__ float tile[32][65];
    const int c = blockIdx.x;                 // k-window [c*32, c*32+32)
    const int t = threadIdx.x;
    if (c == 0 && t == 0) *flag_cnt = 0;
    {
        const int r = t >> 3, q = t & 7;
        float4 v0 = *reinterpret_cast<const float4*>(
            &W[(size_t)(c * 32 + r) * NEXP + q * 8]);
        float4 v1 = *reinterpret_cast<const float4*>(
            &W[(size_t)(c * 32 + r) * NEXP + q * 8 + 4]);
        tile[r][q * 8 + 0] = v0.x; tile[r][q * 8 + 1] = v0.y;
        tile[r][q * 8 + 2] = v0.z; tile[r][q * 8 + 3] = v0.w;
        tile[r][q * 8 + 4] = v1.x; tile[r][q * 8 + 5] = v1.y;
        tile[r][q * 8 + 6] = v1.z; tile[r][q * 8 + 7] = v1.w;
    }
    __syncthreads();
    {
        const int e = t & 63, kgrp = t >> 6;  // 64 experts x 4 k-granules
        const int swz = (e & 7) << 4;
        short8 hv, lv;
#pragma unroll
        for (int j = 0; j < 8; ++j) {
            float f = tile[kgrp * 8 + j][e];
            CVT1(f, hv, lv, j);
        }
        unsigned char* row = blob + (size_t)c * 8192 + e * 128;
        *reinterpret_cast<short8*>(row + ((kgrp * 16) ^ swz))      = hv;
        *reinterpret_cast<short8*>(row + ((64 + kgrp * 16) ^ swz)) = lv;
    }
}

// ---------------------------------------------------------------------------
// Kernel 1: 6-deep counted-vmcnt pipelined MFMA GEMM (T3+T4).
// 512 blocks x 256 thr (4 waves = 2 tokgrp x 2 exphalf).
// Wave = 16 tok x 32 exp, full K in-register (no reduce).
// Per iter: [s_waitcnt vmcnt(N); s_barrier] [COMPUTE(c)] [STAGE(c+5)].
// Loads for steps c+1..c+4 stay in flight across the barrier (never drain 0).
// ---------------------------------------------------------------------------
__global__ __launch_bounds__(256, 2) void bulk_kernel(
    const float* __restrict__ x, const unsigned char* __restrict__ blob,
    const float* __restrict__ b,
    float* __restrict__ g_out, float* __restrict__ i_out,
    float* __restrict__ s_out,
    int* __restrict__ flag_cnt, int* __restrict__ flag_list, int flag_cap)
{
    __shared__ __align__(16) unsigned char smem[NBUF * BUFSZ];   // 72 KB

    const int tid  = threadIdx.x;
    const int l    = tid & 63;
    const int w    = tid >> 6;
    const int tok0 = blockIdx.x * TPB;

    // ---- staging sources: A pre-swizzled per-lane (m173); B linear ----
    const int sTok = tid >> 3;                       // 0..31
    const int sCol = ((tid & 7) * 16) ^ ((sTok & 7) << 4);
    const float* aSrc = x + (size_t)(tok0 + sTok) * DDIM + (sCol >> 2);
    const unsigned char* bSrc = blob + tid * 16;

#define STAGE(buf, s) do {                                                    \
    unsigned char* _d = smem + (buf) * BUFSZ;                                 \
    gload16(aSrc + (size_t)(s) * BK, _d + tid * 16);                          \
    gload16(bSrc + (size_t)(s) * 8192,        _d + 4096 + tid * 16);          \
    gload16(bSrc + (size_t)(s) * 8192 + 4096, _d + 8192 + tid * 16);          \
} while (0)

    // ---- compute-lane constants ----
    const int tg   = w & 1;                  // token group (16 tokens)
    const int egh  = w >> 1;                 // expert half (32 experts)
    const int mt   = l & 15;
    const int kgrp = l >> 4;
    const int arow = tg * 16 + mt;
    const int aoff0 = arow * 128 + ((kgrp * 32) ^ ((arow & 7) << 4));
    const int aoff1 = arow * 128 + ((kgrp * 32 + 16) ^ ((arow & 7) << 4));
    const int e0   = egh * 32 + mt;
    const int bswz = (e0 & 7) << 4;          // same for e0 and e0+16
    const int boffh = e0 * 128 + ((kgrp * 16) ^ bswz);
    const int boffl = e0 * 128 + ((64 + kgrp * 16) ^ bswz);

    f32x4 acc0 = (f32x4){0.f, 0.f, 0.f, 0.f};
    f32x4 acc1 = (f32x4){0.f, 0.f, 0.f, 0.f};

#define COMPUTE(buf) do {                                                     \
    const unsigned char* _a = smem + (buf) * BUFSZ;                           \
    const unsigned char* _b = _a + 4096;                                      \
    float4 A0 = *reinterpret_cast<const float4*>(_a + aoff0);                 \
    float4 A1 = *reinterpret_cast<const float4*>(_a + aoff1);                 \
    short8 bh0 = *reinterpret_cast<const short8*>(_b + boffh);                \
    short8 bl0 = *reinterpret_cast<const short8*>(_b + boffl);                \
    short8 bh1 = *reinterpret_cast<const short8*>(_b + boffh + 2048);         \
    short8 bl1 = *reinterpret_cast<const short8*>(_b + boffl + 2048);         \
    short8 ah, al;                                                            \
    CONV8(A0, A1, ah, al);                                                    \
    acc0 = __builtin_amdgcn_mfma_f32_16x16x32_bf16(ah, bh0, acc0, 0, 0, 0);   \
    acc0 = __builtin_amdgcn_mfma_f32_16x16x32_bf16(ah, bl0, acc0, 0, 0, 0);   \
    acc0 = __builtin_amdgcn_mfma_f32_16x16x32_bf16(al, bh0, acc0, 0, 0, 0);   \
    acc1 = __builtin_amdgcn_mfma_f32_16x16x32_bf16(ah, bh1, acc1, 0, 0, 0);   \
    acc1 = __builtin_amdgcn_mfma_f32_16x16x32_bf16(ah, bl1, acc1, 0, 0, 0);   \
    acc1 = __builtin_amdgcn_mfma_f32_16x16x32_bf16(al, bh1, acc1, 0, 0, 0);   \
} while (0)

#define WAITBAR(n) asm volatile("s_waitcnt vmcnt(" #n ")\n\ts_barrier" ::: "memory")

    // prologue: fill 5 buffers (15 loads outstanding per thread)
    STAGE(0, 0); STAGE(1, 1); STAGE(2, 2); STAGE(3, 3); STAGE(4, 4);

    int cb = 0, sb = 5;
    for (int c = 0; c < NSTEP - 5; ++c) {            // c = 0..122
        WAITBAR(12);                                 // step c landed everywhere
        COMPUTE(cb);
        STAGE(sb, c + 5);                            // overwrites buf (c-1)%6: safe
        cb = (cb == NBUF - 1) ? 0 : cb + 1;
        sb = (sb == NBUF - 1) ? 0 : sb + 1;
    }
    // tail: steps 123..127, outstanding 15/12/9/6/3 at entry
    WAITBAR(12); COMPUTE(cb); cb = (cb == NBUF - 1) ? 0 : cb + 1;
    WAITBAR(9);  COMPUTE(cb); cb = (cb == NBUF - 1) ? 0 : cb + 1;
    WAITBAR(6);  COMPUTE(cb); cb = (cb == NBUF - 1) ? 0 : cb + 1;
    WAITBAR(3);  COMPUTE(cb); cb = (cb == NBUF - 1) ? 0 : cb + 1;
    WAITBAR(0);  COMPUTE(cb);
    __syncthreads();                                 // all compute done; LDS free

    // ---- epilogue: bias + logits into ls (stride 68 keeps 16B align) ----
    float* ls = (float*)smem;                        // [32][68]
    {
        const float beA = b[e0];
        const float beB = b[e0 + 16];
#pragma unroll
        for (int r = 0; r < 4; ++r) {
            const int t_ = tg * 16 + kgrp * 4 + r;
            ls[t_ * 68 + e0]      = acc0[r] + beA;
            ls[t_ * 68 + e0 + 16] = acc1[r] + beB;
        }
    }
    __syncthreads();

    // ---- sigmoid + coalesced s_out write ----
    {
        const int t  = tid >> 3;                     // token 0..31
        const int c0 = (tid & 7) * 8;                // expert base
        float4 v0 = *reinterpret_cast<const float4*>(&ls[t * 68 + c0]);
        float4 v1 = *reinterpret_cast<const float4*>(&ls[t * 68 + c0 + 4]);
        float4 s0, s1;
        s0.x = 1.0f / (1.0f + __expf(-v0.x)); s0.y = 1.0f / (1.0f + __expf(-v0.y));
        s0.z = 1.0f / (1.0f + __expf(-v0.z)); s0.w = 1.0f / (1.0f + __expf(-v0.w));
        s1.x = 1.0f / (1.0f + __expf(-v1.x)); s1.y = 1.0f / (1.0f + __expf(-v1.y));
        s1.z = 1.0f / (1.0f + __expf(-v1.z)); s1.w = 1.0f / (1.0f + __expf(-v1.w));
        float* dst = &s_out[(size_t)(tok0 + t) * NEXP + c0];
        *reinterpret_cast<float4*>(dst)     = s0;
        *reinterpret_cast<float4*>(dst + 4) = s1;
    }

    // ---- top-10 scan, one lane per token ----
    if (tid < TPB) {
        const int t = tid;
        float val[10];
        int   idx[10];
#pragma unroll
        for (int j = 0; j < 10; ++j) { val[j] = -1e30f; idx[j] = 0; }

        for (int e = 0; e < NEXP; ++e) {
            float v = ls[t * 68 + e];
            int  ei = e;
#pragma unroll
            for (int j = 0; j < 10; ++j) {
                if (v > val[j]) {    // strict > keeps lower index first on ties
                    float tv = val[j]; val[j] = v; v = tv;
                    int   ti = idx[j]; idx[j] = ei; ei = ti;
                }
            }
        }

        bool flag = false;
#pragma unroll
        for (int j = 0; j < 9; ++j) flag |= (val[j] - val[j + 1]) < EPS_GAP;

        float g[TOPK], gsum = 0.0f;
#pragma unroll
        for (int j = 0; j < TOPK; ++j) {
            g[j] = 1.0f / (1.0f + __expf(-val[j]));
            gsum += g[j];
        }
        const float inv = 1.0f / gsum;
        const int tg_ = tok0 + t;
#pragma unroll
        for (int j = 0; j < TOPK; ++j) {
            g_out[(size_t)tg_ * TOPK + j] = g[j] * inv;
            i_out[(size_t)tg_ * TOPK + j] = (float)idx[j];
        }
        if (flag) {
            int p = atomicAdd(flag_cnt, 1);
            if (p < flag_cap) flag_list[p] = tg_;
        }
    }
#undef STAGE
#undef COMPUTE
#undef WAITBAR
}

// ---------------------------------------------------------------------------
// Kernel 2: f64-exact re-rank of ambiguous tokens.
// ---------------------------------------------------------------------------
__global__ __launch_bounds__(256) void refine_kernel(
    const float* __restrict__ x, const float* __restrict__ W,
    const float* __restrict__ b, float* __restrict__ g_out,
    float* __restrict__ i_out, float* __restrict__ s_out,
    const int* __restrict__ flag_cnt, const int* __restrict__ flag_list,
    int flag_cap)
{
    __shared__ float  xs2[DDIM];
    __shared__ double red[4][NEXP];
    __shared__ double sc[NEXP];

    const int tid = threadIdx.x;
    int count = *flag_cnt;
    if (count > flag_cap) count = flag_cap;

    for (int it = blockIdx.x; it < count; it += gridDim.x) {
        const int tok = flag_list[it];
        __syncthreads();
#pragma unroll
        for (int q = 0; q < 4; ++q) {
            int fi = tid + 256 * q;
            *reinterpret_cast<float4*>(&xs2[fi * 4]) =
                *reinterpret_cast<const float4*>(&x[(size_t)tok * DDIM + fi * 4]);
        }
        __syncthreads();

        const int e    = tid & 63;
        const int part = tid >> 6;
        const int dbase = part * (DDIM / 4);
        double a = 0.0;
        for (int d = 0; d < DDIM / 4; ++d) {
            a = fma((double)xs2[dbase + d],
                    (double)W[(size_t)(dbase + d) * NEXP + e], a);
        }
        red[part][e] = a;
        __syncthreads();

        if (tid < NEXP) {
            double z = ((red[0][tid] + red[1][tid]) +
                        (red[2][tid] + red[3][tid])) + (double)b[tid];
            double s = 1.0 / (1.0 + exp(-z));
            sc[tid] = s;
            s_out[(size_t)tok * NEXP + tid] = (float)s;
        }
        __syncthreads();

        if (tid == 0) {
            double val[TOPK];
            int    idx[TOPK];
#pragma unroll
            for (int j = 0; j < TOPK; ++j) { val[j] = -1e30; idx[j] = 0; }
            for (int e2 = 0; e2 < NEXP; ++e2) {
                double v = sc[e2];
                int   ei = e2;
#pragma unroll
                for (int j = 0; j < TOPK; ++j) {
                    if (v > val[j]) {
                        double tv = val[j]; val[j] = v; v = tv;
                        int    ti = idx[j]; idx[j] = ei; ei = ti;
                    }
                }
            }
            double gsum = 0.0;
#pragma unroll
            for (int j = 0; j < TOPK; ++j) gsum += val[j];
            const double inv = 1.0 / gsum;
#pragma unroll
            for (int j = 0; j < TOPK; ++j) {
                g_out[(size_t)tok * TOPK + j] = (float)(val[j] * inv);
                i_out[(size_t)tok * TOPK + j] = (float)idx[j];
            }
        }
        __syncthreads();
    }
}

// ---------------------------------------------------------------------------
extern "C" void kernel_launch(void* const* d_in, const int* in_sizes, int n_in,
                              void* d_out, int out_size, void* d_ws, size_t ws_size,
                              hipStream_t stream)
{
    (void)in_sizes; (void)n_in; (void)out_size;
    const float* x = (const float*)d_in[0];
    const float* W = (const float*)d_in[1];
    const float* b = (const float*)d_in[2];

    float* g_out = (float*)d_out;                       // [NTOK, 8]
    float* i_out = g_out + (size_t)NTOK * TOPK;         // [NTOK, 8] indices as float
    float* s_out = i_out + (size_t)NTOK * TOPK;         // [NTOK, 64]

    const size_t OFF_BLOB = 131072;
    const size_t WS_NEED  = OFF_BLOB + (size_t)NSTEP * 8192;    // +1 MB blob
    if (ws_size < WS_NEED) return;

    char* ws = (char*)d_ws;
    int* cnt  = (int*)ws;
    int* list = (int*)(ws + 16);
    unsigned char* blob = (unsigned char*)(ws + OFF_BLOB);
    int cap = NTOK;

    prep_w<<<NSTEP, 256, 0, stream>>>(W, blob, cnt);
    bulk_kernel<<<NTOK / TPB, 256, 0, stream>>>(x, blob, b,
                                                g_out, i_out, s_out,
                                                cnt, list, cap);
    refine_kernel<<<256, 256, 0, stream>>>(x, W, b, g_out, i_out, s_out,
                                           cnt, list, cap);
}